// Round 1
// baseline (892.967 us; speedup 1.0000x reference)
//
#include <hip/hip_runtime.h>
#include <math.h>

#define NN 100000
#define EE 1200000
#define DD 64
#define GG 1024
#define LL 3
#define VOCAB 128
#define SCAN_NB 98   // ceil(100000/1024)

// ---------------- encoder: h[n][j] = sum_f emb[f][x_atom[n][f]][j] ----------------
__global__ __launch_bounds__(256) void enc_kernel(const int* __restrict__ x_atom,
                                                  const float* __restrict__ emb,
                                                  float* __restrict__ h) {
    int idx = blockIdx.x * 256 + threadIdx.x;      // n*64 + j
    if (idx >= NN * 64) return;
    int n = idx >> 6, j = idx & 63;
    int v0 = x_atom[n * 3 + 0];
    int v1 = x_atom[n * 3 + 1];
    int v2 = x_atom[n * 3 + 2];
    h[idx] = emb[(0 * VOCAB + v0) * 64 + j]
           + emb[(1 * VOCAB + v1) * 64 + j]
           + emb[(2 * VOCAB + v2) * 64 + j];
}

// ---------------- init: deg=1 (self-loop weight), hist=0, fill=0 ----------------
__global__ __launch_bounds__(256) void init_kernel(float* __restrict__ deg,
                                                   int* __restrict__ hist,
                                                   int* __restrict__ fill) {
    int i = blockIdx.x * 256 + threadIdx.x;
    if (i < 3 * NN) deg[i] = 1.0f;
    if (i < NN) { hist[i] = 0; fill[i] = 0; }
}

// ---------------- degree accumulation + in-degree histogram ----------------
__global__ __launch_bounds__(256) void deg_kernel(const int* __restrict__ ei,
                                                  const float* __restrict__ ea,
                                                  float* __restrict__ deg,
                                                  int* __restrict__ hist) {
    int e = blockIdx.x * 256 + threadIdx.x;
    if (e >= EE) return;
    int d = ei[EE + e];
    float a0 = ea[e * 3 + 0], a1 = ea[e * 3 + 1], a2 = ea[e * 3 + 2];
    atomicAdd(&deg[d], a0);
    atomicAdd(&deg[NN + d], a1);
    atomicAdd(&deg[2 * NN + d], a2);
    atomicAdd(&hist[d], 1);
}

// ---------------- dinv = deg > 0 ? 1/sqrt(deg) : 0 ----------------
__global__ __launch_bounds__(256) void dinv_kernel(const float* __restrict__ deg,
                                                   float* __restrict__ dinv) {
    int i = blockIdx.x * 256 + threadIdx.x;
    if (i >= 3 * NN) return;
    float d = deg[i];
    dinv[i] = (d > 0.f) ? (1.0f / sqrtf(d)) : 0.f;
}

// ---------------- scan stage 1: per-block (1024 items) sums ----------------
__global__ __launch_bounds__(256) void scan1_kernel(const int* __restrict__ hist,
                                                    int* __restrict__ bsum) {
    __shared__ int sd[256];
    int t = threadIdx.x, b = blockIdx.x;
    int base = b * 1024 + t * 4;
    int s = 0;
#pragma unroll
    for (int u = 0; u < 4; ++u) { int i = base + u; if (i < NN) s += hist[i]; }
    sd[t] = s;
    __syncthreads();
    for (int off = 128; off > 0; off >>= 1) {
        if (t < off) sd[t] += sd[t + off];
        __syncthreads();
    }
    if (t == 0) bsum[b] = sd[0];
}

// ---------------- scan stage 2: serial scan of block sums ----------------
__global__ void scan2_kernel(const int* __restrict__ bsum, int* __restrict__ boff,
                             int* __restrict__ rowst) {
    if (threadIdx.x == 0 && blockIdx.x == 0) {
        int acc = 0;
        for (int i = 0; i < SCAN_NB; ++i) { boff[i] = acc; acc += bsum[i]; }
        rowst[NN] = acc;   // == EE
    }
}

// ---------------- scan stage 3: write exclusive prefix (row_start) ----------------
__global__ __launch_bounds__(256) void scan3_kernel(const int* __restrict__ hist,
                                                    const int* __restrict__ boff,
                                                    int* __restrict__ rowst) {
    __shared__ int sd[256];
    int t = threadIdx.x, b = blockIdx.x;
    int base = b * 1024 + t * 4;
    int v[4]; int s = 0;
#pragma unroll
    for (int u = 0; u < 4; ++u) {
        int i = base + u;
        v[u] = (i < NN) ? hist[i] : 0;
        s += v[u];
    }
    sd[t] = s;
    __syncthreads();
    // Hillis-Steele inclusive scan over 256 thread-sums
    for (int off = 1; off < 256; off <<= 1) {
        int a = (t >= off) ? sd[t - off] : 0;
        __syncthreads();
        sd[t] += a;
        __syncthreads();
    }
    int texcl = sd[t] - s;
    int o = boff[b] + texcl;
#pragma unroll
    for (int u = 0; u < 4; ++u) {
        int i = base + u;
        if (i < NN) rowst[i] = o;
        o += v[u];
    }
}

// ---------------- CSR fill: pack (norm0,norm1,norm2,src) per edge ----------------
__global__ __launch_bounds__(256) void fill_kernel(const int* __restrict__ ei,
                                                   const float* __restrict__ ea,
                                                   const float* __restrict__ dinv,
                                                   const int* __restrict__ rowst,
                                                   int* __restrict__ fill,
                                                   float4* __restrict__ pack) {
    int e = blockIdx.x * 256 + threadIdx.x;
    if (e >= EE) return;
    int s = ei[e], d = ei[EE + e];
    float a0 = ea[e * 3 + 0], a1 = ea[e * 3 + 1], a2 = ea[e * 3 + 2];
    float n0 = dinv[s] * a0 * dinv[d];
    float n1 = dinv[NN + s] * a1 * dinv[NN + d];
    float n2 = dinv[2 * NN + s] * a2 * dinv[2 * NN + d];
    int pos = atomicAdd(&fill[d], 1);
    float4 p; p.x = n0; p.y = n1; p.z = n2; p.w = __int_as_float(s);
    pack[rowst[d] + pos] = p;
}

// ---------------- aggregation: one wave per node, agg[n][k*64+j] ----------------
__global__ __launch_bounds__(256) void agg_kernel(const float* __restrict__ h,
                                                  const float4* __restrict__ pack,
                                                  const int* __restrict__ rowst,
                                                  const float* __restrict__ dinv,
                                                  float* __restrict__ agg) {
    int n = (blockIdx.x * 256 + threadIdx.x) >> 6;
    int lane = threadIdx.x & 63;
    if (n >= NN) return;
    float d0 = dinv[n], d1 = dinv[NN + n], d2 = dinv[2 * NN + n];
    float hs = h[(size_t)n * 64 + lane];
    // self-loop: weight 1, norm = dinv*dinv
    float a0 = hs * d0 * d0;
    float a1 = hs * d1 * d1;
    float a2 = hs * d2 * d2;
    int s0 = rowst[n], s1 = rowst[n + 1];
    for (int s = s0; s < s1; ++s) {
        float4 p = pack[s];
        int src = __float_as_int(p.w);
        float hv = h[(size_t)src * 64 + lane];
        a0 = fmaf(hv, p.x, a0);
        a1 = fmaf(hv, p.y, a1);
        a2 = fmaf(hv, p.z, a2);
    }
    agg[(size_t)n * 192 + lane]       = a0;
    agg[(size_t)n * 192 + 64 + lane]  = a1;
    agg[(size_t)n * 192 + 128 + lane] = a2;
}

// ---------------- fused GEMM: h_new = relu?(agg[N,192]@Wcat[192,64] + bsum) + h ----------------
__global__ __launch_bounds__(256) void gemm_kernel(const float* __restrict__ agg,
                                                   const float* __restrict__ convW,
                                                   const float* __restrict__ convb,
                                                   float* __restrict__ h,
                                                   int layer, int dorelu) {
    __shared__ float an[64][68];    // agg chunk [node][k]   (+pad: stride 68 -> 2-way max on reads)
    __shared__ float ws[64][64];    // W chunk   [k][col]
    int t = threadIdx.x;
    int n0 = blockIdx.x * 64;
    const float* W = convW + (size_t)layer * 192 * 64;
    const float* B = convb + (size_t)layer * 192;
    int nb = t >> 4, cb = t & 15;
    float acc[4][4] = {{0.f}};

    for (int kc = 0; kc < 3; ++kc) {
        __syncthreads();
#pragma unroll
        for (int rep = 0; rep < 16; ++rep) {
            int flat = rep * 256 + t;        // 0..4095
            int r = flat >> 6, i = flat & 63;
            int n = n0 + r;
            an[r][i] = (n < NN) ? agg[(size_t)n * 192 + kc * 64 + i] : 0.f;
            ((float*)ws)[flat] = W[kc * 4096 + flat];
        }
        __syncthreads();
#pragma unroll 4
        for (int i = 0; i < 64; ++i) {
            float4 wv = *(const float4*)&ws[i][cb * 4];
#pragma unroll
            for (int r = 0; r < 4; ++r) {
                float a = an[nb * 4 + r][i];
                acc[r][0] = fmaf(a, wv.x, acc[r][0]);
                acc[r][1] = fmaf(a, wv.y, acc[r][1]);
                acc[r][2] = fmaf(a, wv.z, acc[r][2]);
                acc[r][3] = fmaf(a, wv.w, acc[r][3]);
            }
        }
    }

    int col0 = cb * 4;
    float bs[4];
#pragma unroll
    for (int c = 0; c < 4; ++c) {
        int col = col0 + c;
        bs[c] = B[col] + B[64 + col] + B[128 + col];
    }
#pragma unroll
    for (int r = 0; r < 4; ++r) {
        int n = n0 + nb * 4 + r;
        if (n < NN) {
            float4 hv = *(const float4*)&h[(size_t)n * 64 + col0];
            float v0 = acc[r][0] + bs[0];
            float v1 = acc[r][1] + bs[1];
            float v2 = acc[r][2] + bs[2];
            float v3 = acc[r][3] + bs[3];
            if (dorelu) {
                v0 = fmaxf(v0, 0.f); v1 = fmaxf(v1, 0.f);
                v2 = fmaxf(v2, 0.f); v3 = fmaxf(v3, 0.f);
            }
            float4 o;
            o.x = v0 + hv.x; o.y = v1 + hv.y; o.z = v2 + hv.z; o.w = v3 + hv.w;
            *(float4*)&h[(size_t)n * 64 + col0] = o;
        }
    }
}

// ---------------- graph start offsets via binary search (batch is sorted) ----------------
__global__ __launch_bounds__(256) void gstart_kernel(const int* __restrict__ batch,
                                                     int* __restrict__ gstart) {
    int g = blockIdx.x * 256 + threadIdx.x;
    if (g > GG) return;
    int lo = 0, hi = NN;
    while (lo < hi) {
        int mid = (lo + hi) >> 1;
        if (batch[mid] < g) lo = mid + 1; else hi = mid;
    }
    gstart[g] = lo;
}

// ---------------- mean pool: one wave per graph ----------------
__global__ __launch_bounds__(256) void pool_kernel(const float* __restrict__ h,
                                                   const int* __restrict__ gstart,
                                                   float* __restrict__ hg) {
    int g = (blockIdx.x * 256 + threadIdx.x) >> 6;
    int lane = threadIdx.x & 63;
    if (g >= GG) return;
    int s = gstart[g], e = gstart[g + 1];
    float sum = 0.f;
    for (int n = s; n < e; ++n) sum += h[(size_t)n * 64 + lane];
    int cnt = e - s;
    float div = (cnt > 0) ? (float)cnt : 1.0f;
    hg[(size_t)g * 64 + lane] = sum / div;
}

// ---------------- fc: 3 stacked linears, one wave per graph ----------------
__global__ __launch_bounds__(256) void fc_kernel(const float* __restrict__ hg,
                                                 const float* __restrict__ W1, const float* __restrict__ b1,
                                                 const float* __restrict__ W2, const float* __restrict__ b2,
                                                 const float* __restrict__ W3, const float* __restrict__ b3,
                                                 float* __restrict__ out) {
    int g = (blockIdx.x * 256 + threadIdx.x) >> 6;
    int lane = threadIdx.x & 63;
    if (g >= GG) return;
    float x = hg[(size_t)g * 64 + lane];
    float t1 = b1[lane];
    for (int i = 0; i < 64; ++i) t1 = fmaf(__shfl(x, i, 64), W1[i * 64 + lane], t1);
    float t2 = b2[lane];
    for (int i = 0; i < 64; ++i) t2 = fmaf(__shfl(t1, i, 64), W2[i * 64 + lane], t2);
    float p = t2 * W3[lane];
    for (int off = 32; off > 0; off >>= 1) p += __shfl_down(p, off, 64);
    if (lane == 0) out[g] = p + b3[0];
}

extern "C" void kernel_launch(void* const* d_in, const int* in_sizes, int n_in,
                              void* d_out, int out_size, void* d_ws, size_t ws_size,
                              hipStream_t stream) {
    const int*   x_atom = (const int*)d_in[0];
    const int*   ei     = (const int*)d_in[1];
    const float* ea     = (const float*)d_in[2];
    const int*   batch  = (const int*)d_in[3];
    const float* emb    = (const float*)d_in[4];
    const float* convW  = (const float*)d_in[5];
    const float* convb  = (const float*)d_in[6];
    const float* W1 = (const float*)d_in[7];  const float* b1 = (const float*)d_in[8];
    const float* W2 = (const float*)d_in[9];  const float* b2 = (const float*)d_in[10];
    const float* W3 = (const float*)d_in[11]; const float* b3 = (const float*)d_in[12];
    float* out = (float*)d_out;

    char* p = (char*)d_ws;
    auto alloc = [&](size_t bytes) -> void* {
        void* r = (void*)p;
        p += (bytes + 255) & ~(size_t)255;
        return r;
    };
    float*  h     = (float*)alloc((size_t)NN * 64 * 4);       // 25.6 MB
    float*  agg   = (float*)alloc((size_t)NN * 192 * 4);      // 76.8 MB
    float*  deg   = (float*)alloc((size_t)3 * NN * 4);        // 1.2 MB
    float*  dinv  = (float*)alloc((size_t)3 * NN * 4);        // 1.2 MB
    int*    hist  = (int*)alloc((size_t)NN * 4);
    int*    rowst = (int*)alloc((size_t)(NN + 1) * 4);
    int*    fill  = (int*)alloc((size_t)NN * 4);
    float4* pack  = (float4*)alloc((size_t)EE * 16);          // 19.2 MB
    int*    bsum  = (int*)alloc(128 * 4);
    int*    boff  = (int*)alloc(128 * 4);
    int*    gstart= (int*)alloc((size_t)(GG + 1) * 4);
    float*  hg    = (float*)alloc((size_t)GG * 64 * 4);

    // ---- encoder + norm precompute + CSR build (graph-static, once per launch) ----
    enc_kernel<<<(NN * 64) / 256, 256, 0, stream>>>(x_atom, emb, h);
    init_kernel<<<(3 * NN + 255) / 256, 256, 0, stream>>>(deg, hist, fill);
    deg_kernel<<<(EE + 255) / 256, 256, 0, stream>>>(ei, ea, deg, hist);
    dinv_kernel<<<(3 * NN + 255) / 256, 256, 0, stream>>>(deg, dinv);
    scan1_kernel<<<SCAN_NB, 256, 0, stream>>>(hist, bsum);
    scan2_kernel<<<1, 64, 0, stream>>>(bsum, boff, rowst);
    scan3_kernel<<<SCAN_NB, 256, 0, stream>>>(hist, boff, rowst);
    fill_kernel<<<(EE + 255) / 256, 256, 0, stream>>>(ei, ea, dinv, rowst, fill, pack);
    gstart_kernel<<<(GG + 1 + 255) / 256, 256, 0, stream>>>(batch, gstart);

    // ---- 3 GCN layers: aggregate-then-GEMM (linearity refactor) ----
    for (int layer = 0; layer < LL; ++layer) {
        agg_kernel<<<NN / 4, 256, 0, stream>>>(h, pack, rowst, dinv, agg);
        gemm_kernel<<<(NN + 63) / 64, 256, 0, stream>>>(agg, convW, convb, h, layer,
                                                        (layer < LL - 1) ? 1 : 0);
    }

    // ---- pool + fc ----
    pool_kernel<<<GG / 4, 256, 0, stream>>>(h, gstart, hg);
    fc_kernel<<<GG / 4, 256, 0, stream>>>(hg, W1, b1, W2, b2, W3, b3, out);
}

// Round 3
// 747.699 us; speedup vs baseline: 1.1943x; 1.1943x over previous
//
#include <hip/hip_runtime.h>
#include <math.h>

#define NN 100000
#define EE 1200000
#define DD 64
#define GG 1024
#define LL 3
#define VOCAB 128
#define SCAN_NB 98   // ceil(100000/1024)

// ---------------- encoder: h[n][j] = sum_f emb[f][x_atom[n][f]][j] ----------------
__global__ __launch_bounds__(256) void enc_kernel(const int* __restrict__ x_atom,
                                                  const float* __restrict__ emb,
                                                  float* __restrict__ h) {
    int idx = blockIdx.x * 256 + threadIdx.x;      // n*64 + j
    if (idx >= NN * 64) return;
    int n = idx >> 6, j = idx & 63;
    int v0 = x_atom[n * 3 + 0];
    int v1 = x_atom[n * 3 + 1];
    int v2 = x_atom[n * 3 + 2];
    h[idx] = emb[(0 * VOCAB + v0) * 64 + j]
           + emb[(1 * VOCAB + v1) * 64 + j]
           + emb[(2 * VOCAB + v2) * 64 + j];
}

// ---------------- init: hist=0, fill=0 ----------------
__global__ __launch_bounds__(256) void init_kernel(int* __restrict__ hist,
                                                   int* __restrict__ fill) {
    int i = blockIdx.x * 256 + threadIdx.x;
    if (i < NN) { hist[i] = 0; fill[i] = 0; }
}

// ---------------- in-degree histogram (ONLY atomic pass: 1 int atomic/edge) ----------------
__global__ __launch_bounds__(256) void hist_kernel(const int* __restrict__ ei,
                                                   int* __restrict__ hist) {
    int e = blockIdx.x * 256 + threadIdx.x;
    if (e >= EE) return;
    atomicAdd(&hist[ei[EE + e]], 1);
}

// ---------------- scan stage 1: per-block (1024 items) sums ----------------
__global__ __launch_bounds__(256) void scan1_kernel(const int* __restrict__ hist,
                                                    int* __restrict__ bsum) {
    __shared__ int sd[256];
    int t = threadIdx.x, b = blockIdx.x;
    int base = b * 1024 + t * 4;
    int s = 0;
#pragma unroll
    for (int u = 0; u < 4; ++u) { int i = base + u; if (i < NN) s += hist[i]; }
    sd[t] = s;
    __syncthreads();
    for (int off = 128; off > 0; off >>= 1) {
        if (t < off) sd[t] += sd[t + off];
        __syncthreads();
    }
    if (t == 0) bsum[b] = sd[0];
}

// ---------------- scan stage 2: serial scan of block sums ----------------
__global__ void scan2_kernel(const int* __restrict__ bsum, int* __restrict__ boff,
                             int* __restrict__ rowst) {
    if (threadIdx.x == 0 && blockIdx.x == 0) {
        int acc = 0;
        for (int i = 0; i < SCAN_NB; ++i) { boff[i] = acc; acc += bsum[i]; }
        rowst[NN] = acc;   // == EE
    }
}

// ---------------- scan stage 3: write exclusive prefix (row_start) ----------------
__global__ __launch_bounds__(256) void scan3_kernel(const int* __restrict__ hist,
                                                    const int* __restrict__ boff,
                                                    int* __restrict__ rowst) {
    __shared__ int sd[256];
    int t = threadIdx.x, b = blockIdx.x;
    int base = b * 1024 + t * 4;
    int v[4]; int s = 0;
#pragma unroll
    for (int u = 0; u < 4; ++u) {
        int i = base + u;
        v[u] = (i < NN) ? hist[i] : 0;
        s += v[u];
    }
    sd[t] = s;
    __syncthreads();
    // Hillis-Steele inclusive scan over 256 thread-sums
    for (int off = 1; off < 256; off <<= 1) {
        int a = (t >= off) ? sd[t - off] : 0;
        __syncthreads();
        sd[t] += a;
        __syncthreads();
    }
    int texcl = sd[t] - s;
    int o = boff[b] + texcl;
#pragma unroll
    for (int u = 0; u < 4; ++u) {
        int i = base + u;
        if (i < NN) rowst[i] = o;
        o += v[u];
    }
}

// ---------------- CSR fill: pack raw (a0,a1,a2,src) per edge (1 int atomic/edge) ----------------
__global__ __launch_bounds__(256) void fill_kernel(const int* __restrict__ ei,
                                                   const float* __restrict__ ea,
                                                   const int* __restrict__ rowst,
                                                   int* __restrict__ fill,
                                                   float4* __restrict__ pack) {
    int e = blockIdx.x * 256 + threadIdx.x;
    if (e >= EE) return;
    int s = ei[e], d = ei[EE + e];
    float a0 = ea[e * 3 + 0], a1 = ea[e * 3 + 1], a2 = ea[e * 3 + 2];
    int pos = atomicAdd(&fill[d], 1);
    float4 p; p.x = a0; p.y = a1; p.z = a2; p.w = __int_as_float(s);
    pack[rowst[d] + pos] = p;
}

// ---------------- weighted degree via coalesced CSR row-sum + dinv (NO atomics) ----------------
__global__ __launch_bounds__(256) void degdinv_kernel(const float4* __restrict__ pack,
                                                      const int* __restrict__ rowst,
                                                      float* __restrict__ dinv) {
    int n = blockIdx.x * 256 + threadIdx.x;
    if (n >= NN) return;
    int s0 = rowst[n], s1 = rowst[n + 1];
    float d0 = 1.0f, d1 = 1.0f, d2 = 1.0f;   // self-loop weight 1
    for (int s = s0; s < s1; ++s) {
        float4 p = pack[s];
        d0 += p.x; d1 += p.y; d2 += p.z;
    }
    dinv[n]          = (d0 > 0.f) ? (1.0f / sqrtf(d0)) : 0.f;
    dinv[NN + n]     = (d1 > 0.f) ? (1.0f / sqrtf(d1)) : 0.f;
    dinv[2 * NN + n] = (d2 > 0.f) ? (1.0f / sqrtf(d2)) : 0.f;
}

// ---------------- fold SOURCE-side dinv into pack (dst side applied in agg) ----------------
__global__ __launch_bounds__(256) void normpack_kernel(const float* __restrict__ dinv,
                                                       float4* __restrict__ pack) {
    int e = blockIdx.x * 256 + threadIdx.x;
    if (e >= EE) return;
    float4 p = pack[e];
    int s = __float_as_int(p.w);
    p.x *= dinv[s];
    p.y *= dinv[NN + s];
    p.z *= dinv[2 * NN + s];
    pack[e] = p;
}

// ---------------- aggregation: one wave per node, agg[n][k*64+j] ----------------
// pack holds src-side-normalized weights; dst-side dinv applied once at the end.
__global__ __launch_bounds__(256) void agg_kernel(const float* __restrict__ h,
                                                  const float4* __restrict__ pack,
                                                  const int* __restrict__ rowst,
                                                  const float* __restrict__ dinv,
                                                  float* __restrict__ agg) {
    int n = (blockIdx.x * 256 + threadIdx.x) >> 6;
    int lane = threadIdx.x & 63;
    if (n >= NN) return;
    float d0 = dinv[n], d1 = dinv[NN + n], d2 = dinv[2 * NN + n];
    float hs = h[(size_t)n * 64 + lane];
    // self-loop: src-side factor = dinv_k[n] (weight 1)
    float a0 = hs * d0;
    float a1 = hs * d1;
    float a2 = hs * d2;
    int s0 = rowst[n], s1 = rowst[n + 1];
    for (int s = s0; s < s1; ++s) {
        float4 p = pack[s];
        int src = __float_as_int(p.w);
        float hv = h[(size_t)src * 64 + lane];
        a0 = fmaf(hv, p.x, a0);
        a1 = fmaf(hv, p.y, a1);
        a2 = fmaf(hv, p.z, a2);
    }
    agg[(size_t)n * 192 + lane]       = a0 * d0;
    agg[(size_t)n * 192 + 64 + lane]  = a1 * d1;
    agg[(size_t)n * 192 + 128 + lane] = a2 * d2;
}

// ---------------- fused GEMM: h_new = relu?(agg[N,192]@Wcat[192,64] + bsum) + h ----------------
__global__ __launch_bounds__(256) void gemm_kernel(const float* __restrict__ agg,
                                                   const float* __restrict__ convW,
                                                   const float* __restrict__ convb,
                                                   float* __restrict__ h,
                                                   int layer, int dorelu) {
    __shared__ float an[64][68];    // agg chunk [node][k]   (+pad)
    __shared__ float ws[64][64];    // W chunk   [k][col]
    int t = threadIdx.x;
    int n0 = blockIdx.x * 64;
    const float* W = convW + (size_t)layer * 192 * 64;
    const float* B = convb + (size_t)layer * 192;
    int nb = t >> 4, cb = t & 15;
    float acc[4][4] = {{0.f}};

    for (int kc = 0; kc < 3; ++kc) {
        __syncthreads();
#pragma unroll
        for (int rep = 0; rep < 16; ++rep) {
            int flat = rep * 256 + t;        // 0..4095
            int r = flat >> 6, i = flat & 63;
            int n = n0 + r;
            an[r][i] = (n < NN) ? agg[(size_t)n * 192 + kc * 64 + i] : 0.f;
            ((float*)ws)[flat] = W[kc * 4096 + flat];
        }
        __syncthreads();
#pragma unroll 4
        for (int i = 0; i < 64; ++i) {
            float4 wv = *(const float4*)&ws[i][cb * 4];
#pragma unroll
            for (int r = 0; r < 4; ++r) {
                float a = an[nb * 4 + r][i];
                acc[r][0] = fmaf(a, wv.x, acc[r][0]);
                acc[r][1] = fmaf(a, wv.y, acc[r][1]);
                acc[r][2] = fmaf(a, wv.z, acc[r][2]);
                acc[r][3] = fmaf(a, wv.w, acc[r][3]);
            }
        }
    }

    int col0 = cb * 4;
    float bs[4];
#pragma unroll
    for (int c = 0; c < 4; ++c) {
        int col = col0 + c;
        bs[c] = B[col] + B[64 + col] + B[128 + col];
    }
#pragma unroll
    for (int r = 0; r < 4; ++r) {
        int n = n0 + nb * 4 + r;
        if (n < NN) {
            float4 hv = *(const float4*)&h[(size_t)n * 64 + col0];
            float v0 = acc[r][0] + bs[0];
            float v1 = acc[r][1] + bs[1];
            float v2 = acc[r][2] + bs[2];
            float v3 = acc[r][3] + bs[3];
            if (dorelu) {
                v0 = fmaxf(v0, 0.f); v1 = fmaxf(v1, 0.f);
                v2 = fmaxf(v2, 0.f); v3 = fmaxf(v3, 0.f);
            }
            float4 o;
            o.x = v0 + hv.x; o.y = v1 + hv.y; o.z = v2 + hv.z; o.w = v3 + hv.w;
            *(float4*)&h[(size_t)n * 64 + col0] = o;
        }
    }
}

// ---------------- graph start offsets via binary search (batch is sorted) ----------------
__global__ __launch_bounds__(256) void gstart_kernel(const int* __restrict__ batch,
                                                     int* __restrict__ gstart) {
    int g = blockIdx.x * 256 + threadIdx.x;
    if (g > GG) return;
    int lo = 0, hi = NN;
    while (lo < hi) {
        int mid = (lo + hi) >> 1;
        if (batch[mid] < g) lo = mid + 1; else hi = mid;
    }
    gstart[g] = lo;
}

// ---------------- mean pool: one wave per graph ----------------
__global__ __launch_bounds__(256) void pool_kernel(const float* __restrict__ h,
                                                   const int* __restrict__ gstart,
                                                   float* __restrict__ hg) {
    int g = (blockIdx.x * 256 + threadIdx.x) >> 6;
    int lane = threadIdx.x & 63;
    if (g >= GG) return;
    int s = gstart[g], e = gstart[g + 1];
    float sum = 0.f;
    for (int n = s; n < e; ++n) sum += h[(size_t)n * 64 + lane];
    int cnt = e - s;
    float div = (cnt > 0) ? (float)cnt : 1.0f;
    hg[(size_t)g * 64 + lane] = sum / div;
}

// ---------------- fc: 3 stacked linears, one wave per graph ----------------
__global__ __launch_bounds__(256) void fc_kernel(const float* __restrict__ hg,
                                                 const float* __restrict__ W1, const float* __restrict__ b1,
                                                 const float* __restrict__ W2, const float* __restrict__ b2,
                                                 const float* __restrict__ W3, const float* __restrict__ b3,
                                                 float* __restrict__ out) {
    int g = (blockIdx.x * 256 + threadIdx.x) >> 6;
    int lane = threadIdx.x & 63;
    if (g >= GG) return;
    float x = hg[(size_t)g * 64 + lane];
    float t1 = b1[lane];
    for (int i = 0; i < 64; ++i) t1 = fmaf(__shfl(x, i, 64), W1[i * 64 + lane], t1);
    float t2 = b2[lane];
    for (int i = 0; i < 64; ++i) t2 = fmaf(__shfl(t1, i, 64), W2[i * 64 + lane], t2);
    float p = t2 * W3[lane];
    for (int off = 32; off > 0; off >>= 1) p += __shfl_down(p, off, 64);
    if (lane == 0) out[g] = p + b3[0];
}

extern "C" void kernel_launch(void* const* d_in, const int* in_sizes, int n_in,
                              void* d_out, int out_size, void* d_ws, size_t ws_size,
                              hipStream_t stream) {
    const int*   x_atom = (const int*)d_in[0];
    const int*   ei     = (const int*)d_in[1];
    const float* ea     = (const float*)d_in[2];
    const int*   batch  = (const int*)d_in[3];
    const float* emb    = (const float*)d_in[4];
    const float* convW  = (const float*)d_in[5];
    const float* convb  = (const float*)d_in[6];
    const float* W1 = (const float*)d_in[7];  const float* b1 = (const float*)d_in[8];
    const float* W2 = (const float*)d_in[9];  const float* b2 = (const float*)d_in[10];
    const float* W3 = (const float*)d_in[11]; const float* b3 = (const float*)d_in[12];
    float* out = (float*)d_out;

    char* p = (char*)d_ws;
    auto alloc = [&](size_t bytes) -> void* {
        void* r = (void*)p;
        p += (bytes + 255) & ~(size_t)255;
        return r;
    };
    float*  h     = (float*)alloc((size_t)NN * 64 * 4);       // 25.6 MB
    float*  agg   = (float*)alloc((size_t)NN * 192 * 4);      // 76.8 MB
    float*  dinv  = (float*)alloc((size_t)3 * NN * 4);        // 1.2 MB
    int*    hist  = (int*)alloc((size_t)NN * 4);
    int*    rowst = (int*)alloc((size_t)(NN + 1) * 4);
    int*    fill  = (int*)alloc((size_t)NN * 4);
    float4* pack  = (float4*)alloc((size_t)EE * 16);          // 19.2 MB
    int*    bsum  = (int*)alloc(128 * 4);
    int*    boff  = (int*)alloc(128 * 4);
    int*    gstart= (int*)alloc((size_t)(GG + 1) * 4);
    float*  hg    = (float*)alloc((size_t)GG * 64 * 4);

    // ---- encoder + CSR build (no float atomics anywhere) ----
    enc_kernel<<<(NN * 64) / 256, 256, 0, stream>>>(x_atom, emb, h);
    init_kernel<<<(NN + 255) / 256, 256, 0, stream>>>(hist, fill);
    hist_kernel<<<(EE + 255) / 256, 256, 0, stream>>>(ei, hist);
    scan1_kernel<<<SCAN_NB, 256, 0, stream>>>(hist, bsum);
    scan2_kernel<<<1, 64, 0, stream>>>(bsum, boff, rowst);
    scan3_kernel<<<SCAN_NB, 256, 0, stream>>>(hist, boff, rowst);
    fill_kernel<<<(EE + 255) / 256, 256, 0, stream>>>(ei, ea, rowst, fill, pack);
    degdinv_kernel<<<(NN + 255) / 256, 256, 0, stream>>>(pack, rowst, dinv);
    normpack_kernel<<<(EE + 255) / 256, 256, 0, stream>>>(dinv, pack);
    gstart_kernel<<<(GG + 1 + 255) / 256, 256, 0, stream>>>(batch, gstart);

    // ---- 3 GCN layers: aggregate-then-GEMM (linearity refactor) ----
    for (int layer = 0; layer < LL; ++layer) {
        agg_kernel<<<NN / 4, 256, 0, stream>>>(h, pack, rowst, dinv, agg);
        gemm_kernel<<<(NN + 63) / 64, 256, 0, stream>>>(agg, convW, convb, h, layer,
                                                        (layer < LL - 1) ? 1 : 0);
    }

    // ---- pool + fc ----
    pool_kernel<<<GG / 4, 256, 0, stream>>>(h, gstart, hg);
    fc_kernel<<<GG / 4, 256, 0, stream>>>(hg, W1, b1, W2, b2, W3, b3, out);
}

// Round 4
// 603.849 us; speedup vs baseline: 1.4788x; 1.2382x over previous
//
#include <hip/hip_runtime.h>
#include <math.h>

#define NN 100000
#define EE 1200000
#define DD 64
#define GG 1024
#define LL 3
#define VOCAB 128
#define SCAN_NB 98   // ceil(100000/1024)

// ---------------- encoder: h[n][j] = sum_f emb[f][x_atom[n][f]][j] ----------------
__global__ __launch_bounds__(256) void enc_kernel(const int* __restrict__ x_atom,
                                                  const float* __restrict__ emb,
                                                  float* __restrict__ h) {
    int idx = blockIdx.x * 256 + threadIdx.x;      // n*64 + j
    if (idx >= NN * 64) return;
    int n = idx >> 6, j = idx & 63;
    int v0 = x_atom[n * 3 + 0];
    int v1 = x_atom[n * 3 + 1];
    int v2 = x_atom[n * 3 + 2];
    h[idx] = emb[(0 * VOCAB + v0) * 64 + j]
           + emb[(1 * VOCAB + v1) * 64 + j]
           + emb[(2 * VOCAB + v2) * 64 + j];
}

// ---------------- init: hist=0, fill=0 ----------------
__global__ __launch_bounds__(256) void init_kernel(int* __restrict__ hist,
                                                   int* __restrict__ fill) {
    int i = blockIdx.x * 256 + threadIdx.x;
    if (i < NN) { hist[i] = 0; fill[i] = 0; }
}

// ---------------- in-degree histogram (1 int atomic/edge) ----------------
__global__ __launch_bounds__(256) void hist_kernel(const int* __restrict__ ei,
                                                   int* __restrict__ hist) {
    int e = blockIdx.x * 256 + threadIdx.x;
    if (e >= EE) return;
    atomicAdd(&hist[ei[EE + e]], 1);
}

// ---------------- scan stage 1: per-block (1024 items) sums ----------------
__global__ __launch_bounds__(256) void scan1_kernel(const int* __restrict__ hist,
                                                    int* __restrict__ bsum) {
    __shared__ int sd[256];
    int t = threadIdx.x, b = blockIdx.x;
    int base = b * 1024 + t * 4;
    int s = 0;
#pragma unroll
    for (int u = 0; u < 4; ++u) { int i = base + u; if (i < NN) s += hist[i]; }
    sd[t] = s;
    __syncthreads();
    for (int off = 128; off > 0; off >>= 1) {
        if (t < off) sd[t] += sd[t + off];
        __syncthreads();
    }
    if (t == 0) bsum[b] = sd[0];
}

// ---------------- scan stage 2: serial scan of block sums ----------------
__global__ void scan2_kernel(const int* __restrict__ bsum, int* __restrict__ boff,
                             int* __restrict__ rowst) {
    if (threadIdx.x == 0 && blockIdx.x == 0) {
        int acc = 0;
        for (int i = 0; i < SCAN_NB; ++i) { boff[i] = acc; acc += bsum[i]; }
        rowst[NN] = acc;   // == EE
    }
}

// ---------------- scan stage 3: write exclusive prefix (row_start) ----------------
__global__ __launch_bounds__(256) void scan3_kernel(const int* __restrict__ hist,
                                                    const int* __restrict__ boff,
                                                    int* __restrict__ rowst) {
    __shared__ int sd[256];
    int t = threadIdx.x, b = blockIdx.x;
    int base = b * 1024 + t * 4;
    int v[4]; int s = 0;
#pragma unroll
    for (int u = 0; u < 4; ++u) {
        int i = base + u;
        v[u] = (i < NN) ? hist[i] : 0;
        s += v[u];
    }
    sd[t] = s;
    __syncthreads();
    // Hillis-Steele inclusive scan over 256 thread-sums
    for (int off = 1; off < 256; off <<= 1) {
        int a = (t >= off) ? sd[t - off] : 0;
        __syncthreads();
        sd[t] += a;
        __syncthreads();
    }
    int texcl = sd[t] - s;
    int o = boff[b] + texcl;
#pragma unroll
    for (int u = 0; u < 4; ++u) {
        int i = base + u;
        if (i < NN) rowst[i] = o;
        o += v[u];
    }
}

// ---------------- CSR fill: pack raw (a0,a1,a2,src) per edge (1 int atomic/edge) ----------------
__global__ __launch_bounds__(256) void fill_kernel(const int* __restrict__ ei,
                                                   const float* __restrict__ ea,
                                                   const int* __restrict__ rowst,
                                                   int* __restrict__ fill,
                                                   float4* __restrict__ pack) {
    int e = blockIdx.x * 256 + threadIdx.x;
    if (e >= EE) return;
    int s = ei[e], d = ei[EE + e];
    float a0 = ea[e * 3 + 0], a1 = ea[e * 3 + 1], a2 = ea[e * 3 + 2];
    int pos = atomicAdd(&fill[d], 1);
    float4 p; p.x = a0; p.y = a1; p.z = a2; p.w = __int_as_float(s);
    pack[rowst[d] + pos] = p;
}

// ---------------- weighted degree: 16-lane group per node, parallel row-sum ----------------
__global__ __launch_bounds__(256) void degdinv_kernel(const float4* __restrict__ pack,
                                                      const int* __restrict__ rowst,
                                                      float* __restrict__ dinv) {
    int n   = (blockIdx.x * 256 + threadIdx.x) >> 4;   // 16-lane group per node
    int sub = threadIdx.x & 15;
    if (n >= NN) return;
    int s0 = rowst[n], s1 = rowst[n + 1];
    float d0 = 0.f, d1 = 0.f, d2 = 0.f;
    for (int s = s0 + sub; s < s1; s += 16) {
        float4 p = pack[s];
        d0 += p.x; d1 += p.y; d2 += p.z;
    }
    // reduce within the 16-lane group
#pragma unroll
    for (int off = 8; off > 0; off >>= 1) {
        d0 += __shfl_down(d0, off, 16);
        d1 += __shfl_down(d1, off, 16);
        d2 += __shfl_down(d2, off, 16);
    }
    if (sub == 0) {
        d0 += 1.0f; d1 += 1.0f; d2 += 1.0f;   // self-loop weight 1
        dinv[n]          = 1.0f / sqrtf(d0);  // d >= 1 always
        dinv[NN + n]     = 1.0f / sqrtf(d1);
        dinv[2 * NN + n] = 1.0f / sqrtf(d2);
    }
}

// ---------------- fold SOURCE-side dinv into pack (dst side applied in agg) ----------------
__global__ __launch_bounds__(256) void normpack_kernel(const float* __restrict__ dinv,
                                                       float4* __restrict__ pack) {
    int e = blockIdx.x * 256 + threadIdx.x;
    if (e >= EE) return;
    float4 p = pack[e];
    int s = __float_as_int(p.w);
    p.x *= dinv[s];
    p.y *= dinv[NN + s];
    p.z *= dinv[2 * NN + s];
    pack[e] = p;
}

// ---------------- aggregation: one wave per node, batched gathers for MLP ----------------
// pack holds src-side-normalized weights; dst-side dinv applied once at the end.
__global__ __launch_bounds__(256) void agg_kernel(const float* __restrict__ h,
                                                  const float4* __restrict__ pack,
                                                  const int* __restrict__ rowst,
                                                  const float* __restrict__ dinv,
                                                  float* __restrict__ agg) {
    int n = (blockIdx.x * 256 + threadIdx.x) >> 6;
    int lane = threadIdx.x & 63;
    if (n >= NN) return;
    float d0 = dinv[n], d1 = dinv[NN + n], d2 = dinv[2 * NN + n];
    float hs = h[(size_t)n * 64 + lane];
    // self-loop: src-side factor = dinv_k[n] (weight 1)
    float a0 = hs * d0;
    float a1 = hs * d1;
    float a2 = hs * d2;
    int s0 = rowst[n], s1 = rowst[n + 1];
    int s = s0;
    // ---- batch of 8: 8 pack loads, then 8 independent h-gathers in flight ----
    for (; s + 8 <= s1; s += 8) {
        float4 p[8];
#pragma unroll
        for (int u = 0; u < 8; ++u) p[u] = pack[s + u];
        float hv[8];
#pragma unroll
        for (int u = 0; u < 8; ++u)
            hv[u] = h[(size_t)__float_as_int(p[u].w) * 64 + lane];
#pragma unroll
        for (int u = 0; u < 8; ++u) {
            a0 = fmaf(hv[u], p[u].x, a0);
            a1 = fmaf(hv[u], p[u].y, a1);
            a2 = fmaf(hv[u], p[u].z, a2);
        }
    }
    // ---- batch of 4 ----
    for (; s + 4 <= s1; s += 4) {
        float4 p[4];
#pragma unroll
        for (int u = 0; u < 4; ++u) p[u] = pack[s + u];
        float hv[4];
#pragma unroll
        for (int u = 0; u < 4; ++u)
            hv[u] = h[(size_t)__float_as_int(p[u].w) * 64 + lane];
#pragma unroll
        for (int u = 0; u < 4; ++u) {
            a0 = fmaf(hv[u], p[u].x, a0);
            a1 = fmaf(hv[u], p[u].y, a1);
            a2 = fmaf(hv[u], p[u].z, a2);
        }
    }
    // ---- scalar tail ----
    for (; s < s1; ++s) {
        float4 p = pack[s];
        float hv = h[(size_t)__float_as_int(p.w) * 64 + lane];
        a0 = fmaf(hv, p.x, a0);
        a1 = fmaf(hv, p.y, a1);
        a2 = fmaf(hv, p.z, a2);
    }
    agg[(size_t)n * 192 + lane]       = a0 * d0;
    agg[(size_t)n * 192 + 64 + lane]  = a1 * d1;
    agg[(size_t)n * 192 + 128 + lane] = a2 * d2;
}

// ---------------- fused GEMM: h_new = relu?(agg[N,192]@Wcat[192,64] + bsum) + h ----------------
__global__ __launch_bounds__(256) void gemm_kernel(const float* __restrict__ agg,
                                                   const float* __restrict__ convW,
                                                   const float* __restrict__ convb,
                                                   float* __restrict__ h,
                                                   int layer, int dorelu) {
    __shared__ float an[64][68];    // agg chunk [node][k]   (+pad)
    __shared__ float ws[64][64];    // W chunk   [k][col]
    int t = threadIdx.x;
    int n0 = blockIdx.x * 64;
    const float* W = convW + (size_t)layer * 192 * 64;
    const float* B = convb + (size_t)layer * 192;
    int nb = t >> 4, cb = t & 15;
    float acc[4][4] = {{0.f}};

    for (int kc = 0; kc < 3; ++kc) {
        __syncthreads();
#pragma unroll
        for (int rep = 0; rep < 16; ++rep) {
            int flat = rep * 256 + t;        // 0..4095
            int r = flat >> 6, i = flat & 63;
            int n = n0 + r;
            an[r][i] = (n < NN) ? agg[(size_t)n * 192 + kc * 64 + i] : 0.f;
            ((float*)ws)[flat] = W[kc * 4096 + flat];
        }
        __syncthreads();
#pragma unroll 4
        for (int i = 0; i < 64; ++i) {
            float4 wv = *(const float4*)&ws[i][cb * 4];
#pragma unroll
            for (int r = 0; r < 4; ++r) {
                float a = an[nb * 4 + r][i];
                acc[r][0] = fmaf(a, wv.x, acc[r][0]);
                acc[r][1] = fmaf(a, wv.y, acc[r][1]);
                acc[r][2] = fmaf(a, wv.z, acc[r][2]);
                acc[r][3] = fmaf(a, wv.w, acc[r][3]);
            }
        }
    }

    int col0 = cb * 4;
    float bs[4];
#pragma unroll
    for (int c = 0; c < 4; ++c) {
        int col = col0 + c;
        bs[c] = B[col] + B[64 + col] + B[128 + col];
    }
#pragma unroll
    for (int r = 0; r < 4; ++r) {
        int n = n0 + nb * 4 + r;
        if (n < NN) {
            float4 hv = *(const float4*)&h[(size_t)n * 64 + col0];
            float v0 = acc[r][0] + bs[0];
            float v1 = acc[r][1] + bs[1];
            float v2 = acc[r][2] + bs[2];
            float v3 = acc[r][3] + bs[3];
            if (dorelu) {
                v0 = fmaxf(v0, 0.f); v1 = fmaxf(v1, 0.f);
                v2 = fmaxf(v2, 0.f); v3 = fmaxf(v3, 0.f);
            }
            float4 o;
            o.x = v0 + hv.x; o.y = v1 + hv.y; o.z = v2 + hv.z; o.w = v3 + hv.w;
            *(float4*)&h[(size_t)n * 64 + col0] = o;
        }
    }
}

// ---------------- graph start offsets via binary search (batch is sorted) ----------------
__global__ __launch_bounds__(256) void gstart_kernel(const int* __restrict__ batch,
                                                     int* __restrict__ gstart) {
    int g = blockIdx.x * 256 + threadIdx.x;
    if (g > GG) return;
    int lo = 0, hi = NN;
    while (lo < hi) {
        int mid = (lo + hi) >> 1;
        if (batch[mid] < g) lo = mid + 1; else hi = mid;
    }
    gstart[g] = lo;
}

// ---------------- mean pool: one wave per graph ----------------
__global__ __launch_bounds__(256) void pool_kernel(const float* __restrict__ h,
                                                   const int* __restrict__ gstart,
                                                   float* __restrict__ hg) {
    int g = (blockIdx.x * 256 + threadIdx.x) >> 6;
    int lane = threadIdx.x & 63;
    if (g >= GG) return;
    int s = gstart[g], e = gstart[g + 1];
    float sum = 0.f;
    for (int n = s; n < e; ++n) sum += h[(size_t)n * 64 + lane];
    int cnt = e - s;
    float div = (cnt > 0) ? (float)cnt : 1.0f;
    hg[(size_t)g * 64 + lane] = sum / div;
}

// ---------------- fc: 3 stacked linears, one wave per graph ----------------
__global__ __launch_bounds__(256) void fc_kernel(const float* __restrict__ hg,
                                                 const float* __restrict__ W1, const float* __restrict__ b1,
                                                 const float* __restrict__ W2, const float* __restrict__ b2,
                                                 const float* __restrict__ W3, const float* __restrict__ b3,
                                                 float* __restrict__ out) {
    int g = (blockIdx.x * 256 + threadIdx.x) >> 6;
    int lane = threadIdx.x & 63;
    if (g >= GG) return;
    float x = hg[(size_t)g * 64 + lane];
    float t1 = b1[lane];
    for (int i = 0; i < 64; ++i) t1 = fmaf(__shfl(x, i, 64), W1[i * 64 + lane], t1);
    float t2 = b2[lane];
    for (int i = 0; i < 64; ++i) t2 = fmaf(__shfl(t1, i, 64), W2[i * 64 + lane], t2);
    float p = t2 * W3[lane];
    for (int off = 32; off > 0; off >>= 1) p += __shfl_down(p, off, 64);
    if (lane == 0) out[g] = p + b3[0];
}

extern "C" void kernel_launch(void* const* d_in, const int* in_sizes, int n_in,
                              void* d_out, int out_size, void* d_ws, size_t ws_size,
                              hipStream_t stream) {
    const int*   x_atom = (const int*)d_in[0];
    const int*   ei     = (const int*)d_in[1];
    const float* ea     = (const float*)d_in[2];
    const int*   batch  = (const int*)d_in[3];
    const float* emb    = (const float*)d_in[4];
    const float* convW  = (const float*)d_in[5];
    const float* convb  = (const float*)d_in[6];
    const float* W1 = (const float*)d_in[7];  const float* b1 = (const float*)d_in[8];
    const float* W2 = (const float*)d_in[9];  const float* b2 = (const float*)d_in[10];
    const float* W3 = (const float*)d_in[11]; const float* b3 = (const float*)d_in[12];
    float* out = (float*)d_out;

    char* p = (char*)d_ws;
    auto alloc = [&](size_t bytes) -> void* {
        void* r = (void*)p;
        p += (bytes + 255) & ~(size_t)255;
        return r;
    };
    float*  h     = (float*)alloc((size_t)NN * 64 * 4);       // 25.6 MB
    float*  agg   = (float*)alloc((size_t)NN * 192 * 4);      // 76.8 MB
    float*  dinv  = (float*)alloc((size_t)3 * NN * 4);        // 1.2 MB
    int*    hist  = (int*)alloc((size_t)NN * 4);
    int*    rowst = (int*)alloc((size_t)(NN + 1) * 4);
    int*    fill  = (int*)alloc((size_t)NN * 4);
    float4* pack  = (float4*)alloc((size_t)EE * 16);          // 19.2 MB
    int*    bsum  = (int*)alloc(128 * 4);
    int*    boff  = (int*)alloc(128 * 4);
    int*    gstart= (int*)alloc((size_t)(GG + 1) * 4);
    float*  hg    = (float*)alloc((size_t)GG * 64 * 4);

    // ---- encoder + CSR build (no float atomics anywhere) ----
    enc_kernel<<<(NN * 64) / 256, 256, 0, stream>>>(x_atom, emb, h);
    init_kernel<<<(NN + 255) / 256, 256, 0, stream>>>(hist, fill);
    hist_kernel<<<(EE + 255) / 256, 256, 0, stream>>>(ei, hist);
    scan1_kernel<<<SCAN_NB, 256, 0, stream>>>(hist, bsum);
    scan2_kernel<<<1, 64, 0, stream>>>(bsum, boff, rowst);
    scan3_kernel<<<SCAN_NB, 256, 0, stream>>>(hist, boff, rowst);
    fill_kernel<<<(EE + 255) / 256, 256, 0, stream>>>(ei, ea, rowst, fill, pack);
    degdinv_kernel<<<(NN * 16 + 255) / 256, 256, 0, stream>>>(pack, rowst, dinv);
    normpack_kernel<<<(EE + 255) / 256, 256, 0, stream>>>(dinv, pack);
    gstart_kernel<<<(GG + 1 + 255) / 256, 256, 0, stream>>>(batch, gstart);

    // ---- 3 GCN layers: aggregate-then-GEMM (linearity refactor) ----
    for (int layer = 0; layer < LL; ++layer) {
        agg_kernel<<<NN / 4, 256, 0, stream>>>(h, pack, rowst, dinv, agg);
        gemm_kernel<<<(NN + 63) / 64, 256, 0, stream>>>(agg, convW, convb, h, layer,
                                                        (layer < LL - 1) ? 1 : 0);
    }

    // ---- pool + fc ----
    pool_kernel<<<GG / 4, 256, 0, stream>>>(h, gstart, hg);
    fc_kernel<<<GG / 4, 256, 0, stream>>>(hg, W1, b1, W2, b2, W3, b3, out);
}

// Round 5
// 556.216 us; speedup vs baseline: 1.6054x; 1.0856x over previous
//
#include <hip/hip_runtime.h>
#include <math.h>

#define NN 100000
#define EE 1200000
#define DD 64
#define GG 1024
#define LL 3
#define VOCAB 128
#define SCAN_NB 98     // ceil(100000/1024)
#define PSTR 64        // padded CSR row stride (slots/node); Poisson(12) max-deg << 64

// ---------------- encoder: h[n][j] = sum_f emb[f][x_atom[n][f]][j] ----------------
__global__ __launch_bounds__(256) void enc_kernel(const int* __restrict__ x_atom,
                                                  const float* __restrict__ emb,
                                                  float* __restrict__ h) {
    int idx = blockIdx.x * 256 + threadIdx.x;      // n*64 + j
    if (idx >= NN * 64) return;
    int n = idx >> 6, j = idx & 63;
    int v0 = x_atom[n * 3 + 0];
    int v1 = x_atom[n * 3 + 1];
    int v2 = x_atom[n * 3 + 2];
    h[idx] = emb[(0 * VOCAB + v0) * 64 + j]
           + emb[(1 * VOCAB + v1) * 64 + j]
           + emb[(2 * VOCAB + v2) * 64 + j];
}

// ---------------- init: hist=0, fill=0 ----------------
__global__ __launch_bounds__(256) void init_kernel(int* __restrict__ hist,
                                                   int* __restrict__ fill) {
    int i = blockIdx.x * 256 + threadIdx.x;
    if (i < NN) { hist[i] = 0; fill[i] = 0; }
}

// ---------------- in-degree histogram (compact fallback path only) ----------------
__global__ __launch_bounds__(256) void hist_kernel(const int* __restrict__ ei,
                                                   int* __restrict__ hist) {
    int e = blockIdx.x * 256 + threadIdx.x;
    if (e >= EE) return;
    atomicAdd(&hist[ei[EE + e]], 1);
}

// ---------------- scan stage 1 (fallback) ----------------
__global__ __launch_bounds__(256) void scan1_kernel(const int* __restrict__ hist,
                                                    int* __restrict__ bsum) {
    __shared__ int sd[256];
    int t = threadIdx.x, b = blockIdx.x;
    int base = b * 1024 + t * 4;
    int s = 0;
#pragma unroll
    for (int u = 0; u < 4; ++u) { int i = base + u; if (i < NN) s += hist[i]; }
    sd[t] = s;
    __syncthreads();
    for (int off = 128; off > 0; off >>= 1) {
        if (t < off) sd[t] += sd[t + off];
        __syncthreads();
    }
    if (t == 0) bsum[b] = sd[0];
}

// ---------------- scan stage 2 (fallback) ----------------
__global__ void scan2_kernel(const int* __restrict__ bsum, int* __restrict__ boff,
                             int* __restrict__ rowst) {
    if (threadIdx.x == 0 && blockIdx.x == 0) {
        int acc = 0;
        for (int i = 0; i < SCAN_NB; ++i) { boff[i] = acc; acc += bsum[i]; }
        rowst[NN] = acc;   // == EE
    }
}

// ---------------- scan stage 3 (fallback) ----------------
__global__ __launch_bounds__(256) void scan3_kernel(const int* __restrict__ hist,
                                                    const int* __restrict__ boff,
                                                    int* __restrict__ rowst) {
    __shared__ int sd[256];
    int t = threadIdx.x, b = blockIdx.x;
    int base = b * 1024 + t * 4;
    int v[4]; int s = 0;
#pragma unroll
    for (int u = 0; u < 4; ++u) {
        int i = base + u;
        v[u] = (i < NN) ? hist[i] : 0;
        s += v[u];
    }
    sd[t] = s;
    __syncthreads();
    for (int off = 1; off < 256; off <<= 1) {
        int a = (t >= off) ? sd[t - off] : 0;
        __syncthreads();
        sd[t] += a;
        __syncthreads();
    }
    int texcl = sd[t] - s;
    int o = boff[b] + texcl;
#pragma unroll
    for (int u = 0; u < 4; ++u) {
        int i = base + u;
        if (i < NN) rowst[i] = o;
        o += v[u];
    }
}

// ---------------- CSR fill: 4 edges/thread for ILP; 1 int atomic/edge ----------------
// padded: slot = (dst<<6)+pos ; compact: slot = rowst[dst]+pos
__global__ __launch_bounds__(256) void fill_kernel(const int* __restrict__ ei,
                                                   const float* __restrict__ ea,
                                                   const int* __restrict__ rowst,
                                                   int* __restrict__ fill,
                                                   float4* __restrict__ pack,
                                                   int padded) {
    int base = blockIdx.x * 1024 + threadIdx.x;
    int d[4]; float4 p[4]; bool v[4];
#pragma unroll
    for (int u = 0; u < 4; ++u) {
        int e = base + u * 256;
        v[u] = (e < EE);
        if (v[u]) {
            int s = ei[e];
            d[u] = ei[EE + e];
            p[u].x = ea[e * 3 + 0];
            p[u].y = ea[e * 3 + 1];
            p[u].z = ea[e * 3 + 2];
            p[u].w = __int_as_float(s);
        }
    }
    int pos[4];
#pragma unroll
    for (int u = 0; u < 4; ++u)
        if (v[u]) pos[u] = atomicAdd(&fill[d[u]], 1);
#pragma unroll
    for (int u = 0; u < 4; ++u) {
        if (v[u]) {
            if (padded) {
                if (pos[u] < PSTR) pack[((size_t)d[u] << 6) + pos[u]] = p[u];
            } else {
                pack[rowst[d[u]] + pos[u]] = p[u];
            }
        }
    }
}

// ---------------- weighted degree: 16-lane group per node, parallel row-sum ----------------
__global__ __launch_bounds__(256) void degdinv_kernel(const float4* __restrict__ pack,
                                                      const int* __restrict__ rowst,
                                                      const int* __restrict__ cnt,
                                                      float* __restrict__ dinv,
                                                      int padded) {
    int n   = (blockIdx.x * 256 + threadIdx.x) >> 4;   // 16-lane group per node
    int sub = threadIdx.x & 15;
    if (n >= NN) return;
    int s0 = padded ? (n << 6) : rowst[n];
    int s1 = padded ? (s0 + cnt[n]) : rowst[n + 1];
    float d0 = 0.f, d1 = 0.f, d2 = 0.f;
    for (int s = s0 + sub; s < s1; s += 16) {
        float4 p = pack[s];
        d0 += p.x; d1 += p.y; d2 += p.z;
    }
#pragma unroll
    for (int off = 8; off > 0; off >>= 1) {
        d0 += __shfl_down(d0, off, 16);
        d1 += __shfl_down(d1, off, 16);
        d2 += __shfl_down(d2, off, 16);
    }
    if (sub == 0) {
        d0 += 1.0f; d1 += 1.0f; d2 += 1.0f;   // self-loop weight 1
        dinv[n]          = 1.0f / sqrtf(d0);  // deg >= 1 always
        dinv[NN + n]     = 1.0f / sqrtf(d1);
        dinv[2 * NN + n] = 1.0f / sqrtf(d2);
    }
}

// ---------------- fold SOURCE-side dinv into pack (node-parallel over rows) ----------------
__global__ __launch_bounds__(256) void normpack_kernel(const float* __restrict__ dinv,
                                                       const int* __restrict__ rowst,
                                                       const int* __restrict__ cnt,
                                                       float4* __restrict__ pack,
                                                       int padded) {
    int n   = (blockIdx.x * 256 + threadIdx.x) >> 4;
    int sub = threadIdx.x & 15;
    if (n >= NN) return;
    int s0 = padded ? (n << 6) : rowst[n];
    int s1 = padded ? (s0 + cnt[n]) : rowst[n + 1];
    for (int s = s0 + sub; s < s1; s += 16) {
        float4 p = pack[s];
        int src = __float_as_int(p.w);
        p.x *= dinv[src];
        p.y *= dinv[NN + src];
        p.z *= dinv[2 * NN + src];
        pack[s] = p;
    }
}

// ---------------- aggregation: one wave per node, batched gathers for MLP ----------------
__global__ __launch_bounds__(256) void agg_kernel(const float* __restrict__ h,
                                                  const float4* __restrict__ pack,
                                                  const int* __restrict__ rowst,
                                                  const int* __restrict__ cnt,
                                                  const float* __restrict__ dinv,
                                                  float* __restrict__ agg,
                                                  int padded) {
    int n = (blockIdx.x * 256 + threadIdx.x) >> 6;
    int lane = threadIdx.x & 63;
    if (n >= NN) return;
    float d0 = dinv[n], d1 = dinv[NN + n], d2 = dinv[2 * NN + n];
    float hs = h[(size_t)n * 64 + lane];
    float a0 = hs * d0;     // self-loop: src-side factor = dinv_k[n]
    float a1 = hs * d1;
    float a2 = hs * d2;
    int s0 = padded ? (n << 6) : rowst[n];
    int s1 = padded ? (s0 + cnt[n]) : rowst[n + 1];
    int s = s0;
    for (; s + 8 <= s1; s += 8) {
        float4 p[8];
#pragma unroll
        for (int u = 0; u < 8; ++u) p[u] = pack[s + u];
        float hv[8];
#pragma unroll
        for (int u = 0; u < 8; ++u)
            hv[u] = h[(size_t)__float_as_int(p[u].w) * 64 + lane];
#pragma unroll
        for (int u = 0; u < 8; ++u) {
            a0 = fmaf(hv[u], p[u].x, a0);
            a1 = fmaf(hv[u], p[u].y, a1);
            a2 = fmaf(hv[u], p[u].z, a2);
        }
    }
    for (; s + 4 <= s1; s += 4) {
        float4 p[4];
#pragma unroll
        for (int u = 0; u < 4; ++u) p[u] = pack[s + u];
        float hv[4];
#pragma unroll
        for (int u = 0; u < 4; ++u)
            hv[u] = h[(size_t)__float_as_int(p[u].w) * 64 + lane];
#pragma unroll
        for (int u = 0; u < 4; ++u) {
            a0 = fmaf(hv[u], p[u].x, a0);
            a1 = fmaf(hv[u], p[u].y, a1);
            a2 = fmaf(hv[u], p[u].z, a2);
        }
    }
    for (; s < s1; ++s) {
        float4 p = pack[s];
        float hv = h[(size_t)__float_as_int(p.w) * 64 + lane];
        a0 = fmaf(hv, p.x, a0);
        a1 = fmaf(hv, p.y, a1);
        a2 = fmaf(hv, p.z, a2);
    }
    agg[(size_t)n * 192 + lane]       = a0 * d0;
    agg[(size_t)n * 192 + 64 + lane]  = a1 * d1;
    agg[(size_t)n * 192 + 128 + lane] = a2 * d2;
}

// ---------------- fused GEMM: h_new = relu?(agg[N,192]@Wcat[192,64] + bsum) + h ----------------
__global__ __launch_bounds__(256) void gemm_kernel(const float* __restrict__ agg,
                                                   const float* __restrict__ convW,
                                                   const float* __restrict__ convb,
                                                   float* __restrict__ h,
                                                   int layer, int dorelu) {
    __shared__ float an[64][68];    // agg chunk [node][k]   (+pad)
    __shared__ float ws[64][64];    // W chunk   [k][col]
    int t = threadIdx.x;
    int n0 = blockIdx.x * 64;
    const float* W = convW + (size_t)layer * 192 * 64;
    const float* B = convb + (size_t)layer * 192;
    int nb = t >> 4, cb = t & 15;
    float acc[4][4] = {{0.f}};

    for (int kc = 0; kc < 3; ++kc) {
        __syncthreads();
#pragma unroll
        for (int rep = 0; rep < 16; ++rep) {
            int flat = rep * 256 + t;        // 0..4095
            int r = flat >> 6, i = flat & 63;
            int n = n0 + r;
            an[r][i] = (n < NN) ? agg[(size_t)n * 192 + kc * 64 + i] : 0.f;
            ((float*)ws)[flat] = W[kc * 4096 + flat];
        }
        __syncthreads();
#pragma unroll 4
        for (int i = 0; i < 64; ++i) {
            float4 wv = *(const float4*)&ws[i][cb * 4];
#pragma unroll
            for (int r = 0; r < 4; ++r) {
                float a = an[nb * 4 + r][i];
                acc[r][0] = fmaf(a, wv.x, acc[r][0]);
                acc[r][1] = fmaf(a, wv.y, acc[r][1]);
                acc[r][2] = fmaf(a, wv.z, acc[r][2]);
                acc[r][3] = fmaf(a, wv.w, acc[r][3]);
            }
        }
    }

    int col0 = cb * 4;
    float bs[4];
#pragma unroll
    for (int c = 0; c < 4; ++c) {
        int col = col0 + c;
        bs[c] = B[col] + B[64 + col] + B[128 + col];
    }
#pragma unroll
    for (int r = 0; r < 4; ++r) {
        int n = n0 + nb * 4 + r;
        if (n < NN) {
            float4 hv = *(const float4*)&h[(size_t)n * 64 + col0];
            float v0 = acc[r][0] + bs[0];
            float v1 = acc[r][1] + bs[1];
            float v2 = acc[r][2] + bs[2];
            float v3 = acc[r][3] + bs[3];
            if (dorelu) {
                v0 = fmaxf(v0, 0.f); v1 = fmaxf(v1, 0.f);
                v2 = fmaxf(v2, 0.f); v3 = fmaxf(v3, 0.f);
            }
            float4 o;
            o.x = v0 + hv.x; o.y = v1 + hv.y; o.z = v2 + hv.z; o.w = v3 + hv.w;
            *(float4*)&h[(size_t)n * 64 + col0] = o;
        }
    }
}

// ---------------- graph start offsets via binary search (batch is sorted) ----------------
__global__ __launch_bounds__(256) void gstart_kernel(const int* __restrict__ batch,
                                                     int* __restrict__ gstart) {
    int g = blockIdx.x * 256 + threadIdx.x;
    if (g > GG) return;
    int lo = 0, hi = NN;
    while (lo < hi) {
        int mid = (lo + hi) >> 1;
        if (batch[mid] < g) lo = mid + 1; else hi = mid;
    }
    gstart[g] = lo;
}

// ---------------- mean pool: one wave per graph ----------------
__global__ __launch_bounds__(256) void pool_kernel(const float* __restrict__ h,
                                                   const int* __restrict__ gstart,
                                                   float* __restrict__ hg) {
    int g = (blockIdx.x * 256 + threadIdx.x) >> 6;
    int lane = threadIdx.x & 63;
    if (g >= GG) return;
    int s = gstart[g], e = gstart[g + 1];
    float sum = 0.f;
    for (int n = s; n < e; ++n) sum += h[(size_t)n * 64 + lane];
    int cnt = e - s;
    float div = (cnt > 0) ? (float)cnt : 1.0f;
    hg[(size_t)g * 64 + lane] = sum / div;
}

// ---------------- fc: 3 stacked linears, one wave per graph ----------------
__global__ __launch_bounds__(256) void fc_kernel(const float* __restrict__ hg,
                                                 const float* __restrict__ W1, const float* __restrict__ b1,
                                                 const float* __restrict__ W2, const float* __restrict__ b2,
                                                 const float* __restrict__ W3, const float* __restrict__ b3,
                                                 float* __restrict__ out) {
    int g = (blockIdx.x * 256 + threadIdx.x) >> 6;
    int lane = threadIdx.x & 63;
    if (g >= GG) return;
    float x = hg[(size_t)g * 64 + lane];
    float t1 = b1[lane];
    for (int i = 0; i < 64; ++i) t1 = fmaf(__shfl(x, i, 64), W1[i * 64 + lane], t1);
    float t2 = b2[lane];
    for (int i = 0; i < 64; ++i) t2 = fmaf(__shfl(t1, i, 64), W2[i * 64 + lane], t2);
    float p = t2 * W3[lane];
    for (int off = 32; off > 0; off >>= 1) p += __shfl_down(p, off, 64);
    if (lane == 0) out[g] = p + b3[0];
}

extern "C" void kernel_launch(void* const* d_in, const int* in_sizes, int n_in,
                              void* d_out, int out_size, void* d_ws, size_t ws_size,
                              hipStream_t stream) {
    const int*   x_atom = (const int*)d_in[0];
    const int*   ei     = (const int*)d_in[1];
    const float* ea     = (const float*)d_in[2];
    const int*   batch  = (const int*)d_in[3];
    const float* emb    = (const float*)d_in[4];
    const float* convW  = (const float*)d_in[5];
    const float* convb  = (const float*)d_in[6];
    const float* W1 = (const float*)d_in[7];  const float* b1 = (const float*)d_in[8];
    const float* W2 = (const float*)d_in[9];  const float* b2 = (const float*)d_in[10];
    const float* W3 = (const float*)d_in[11]; const float* b3 = (const float*)d_in[12];
    float* out = (float*)d_out;

    char* p = (char*)d_ws;
    size_t used = 0;
    auto alloc = [&](size_t bytes) -> void* {
        void* r = (void*)p;
        size_t rb = (bytes + 255) & ~(size_t)255;
        p += rb; used += rb;
        return r;
    };
    float*  h     = (float*)alloc((size_t)NN * 64 * 4);       // 25.6 MB
    float*  agg   = (float*)alloc((size_t)NN * 192 * 4);      // 76.8 MB
    float*  dinv  = (float*)alloc((size_t)3 * NN * 4);        // 1.2 MB
    int*    hist  = (int*)alloc((size_t)NN * 4);
    int*    rowst = (int*)alloc((size_t)(NN + 1) * 4);
    int*    fill  = (int*)alloc((size_t)NN * 4);
    int*    bsum  = (int*)alloc(128 * 4);
    int*    boff  = (int*)alloc(128 * 4);
    int*    gstart= (int*)alloc((size_t)(GG + 1) * 4);
    float*  hg    = (float*)alloc((size_t)GG * 64 * 4);
    // pack last: padded (102.4 MB) if workspace allows, else compact (19.2 MB)
    size_t padded_bytes  = (size_t)NN * PSTR * 16;
    size_t compact_bytes = (size_t)EE * 16;
    int padded = (ws_size >= used + padded_bytes) ? 1 : 0;
    float4* pack = (float4*)alloc(padded ? padded_bytes : compact_bytes);

    // ---- encoder + CSR build ----
    enc_kernel<<<(NN * 64) / 256, 256, 0, stream>>>(x_atom, emb, h);
    init_kernel<<<(NN + 255) / 256, 256, 0, stream>>>(hist, fill);
    if (!padded) {
        hist_kernel<<<(EE + 255) / 256, 256, 0, stream>>>(ei, hist);
        scan1_kernel<<<SCAN_NB, 256, 0, stream>>>(hist, bsum);
        scan2_kernel<<<1, 64, 0, stream>>>(bsum, boff, rowst);
        scan3_kernel<<<SCAN_NB, 256, 0, stream>>>(hist, boff, rowst);
    }
    fill_kernel<<<(EE + 1023) / 1024, 256, 0, stream>>>(ei, ea, rowst, fill, pack, padded);
    degdinv_kernel<<<(NN * 16 + 255) / 256, 256, 0, stream>>>(pack, rowst, fill, dinv, padded);
    normpack_kernel<<<(NN * 16 + 255) / 256, 256, 0, stream>>>(dinv, rowst, fill, pack, padded);
    gstart_kernel<<<(GG + 1 + 255) / 256, 256, 0, stream>>>(batch, gstart);

    // ---- 3 GCN layers: aggregate-then-GEMM (linearity refactor) ----
    for (int layer = 0; layer < LL; ++layer) {
        agg_kernel<<<NN / 4, 256, 0, stream>>>(h, pack, rowst, fill, dinv, agg, padded);
        gemm_kernel<<<(NN + 63) / 64, 256, 0, stream>>>(agg, convW, convb, h, layer,
                                                        (layer < LL - 1) ? 1 : 0);
    }

    // ---- pool + fc ----
    pool_kernel<<<GG / 4, 256, 0, stream>>>(h, gstart, hg);
    fc_kernel<<<GG / 4, 256, 0, stream>>>(hg, W1, b1, W2, b2, W3, b3, out);
}

// Round 6
// 513.685 us; speedup vs baseline: 1.7384x; 1.0828x over previous
//
#include <hip/hip_runtime.h>
#include <math.h>

#define NN 100000
#define EE 1200000
#define DD 64
#define GG 1024
#define LL 3
#define VOCAB 128
#define SCAN_NB 98     // ceil(100000/1024)
#define PSTR 64        // padded CSR row stride (slots/node); Poisson(12) max-deg << 64
#define FILL_NB 2048   // fill grid: 8 blocks/CU -> max atomic concurrency

// ---------------- encoder: h[n][j] = sum_f emb[f][x_atom[n][f]][j] ----------------
__global__ __launch_bounds__(256) void enc_kernel(const int* __restrict__ x_atom,
                                                  const float* __restrict__ emb,
                                                  float* __restrict__ h) {
    int idx = blockIdx.x * 256 + threadIdx.x;      // n*64 + j
    if (idx >= NN * 64) return;
    int n = idx >> 6, j = idx & 63;
    int v0 = x_atom[n * 3 + 0];
    int v1 = x_atom[n * 3 + 1];
    int v2 = x_atom[n * 3 + 2];
    h[idx] = emb[(0 * VOCAB + v0) * 64 + j]
           + emb[(1 * VOCAB + v1) * 64 + j]
           + emb[(2 * VOCAB + v2) * 64 + j];
}

// ---------------- init: hist=0, fill=0 ----------------
__global__ __launch_bounds__(256) void init_kernel(int* __restrict__ hist,
                                                   int* __restrict__ fill) {
    int i = blockIdx.x * 256 + threadIdx.x;
    if (i < NN) { hist[i] = 0; fill[i] = 0; }
}

// ---------------- in-degree histogram (compact fallback path only) ----------------
__global__ __launch_bounds__(256) void hist_kernel(const int* __restrict__ ei,
                                                   int* __restrict__ hist) {
    int e = blockIdx.x * 256 + threadIdx.x;
    if (e >= EE) return;
    atomicAdd(&hist[ei[EE + e]], 1);
}

// ---------------- scan stage 1 (fallback) ----------------
__global__ __launch_bounds__(256) void scan1_kernel(const int* __restrict__ hist,
                                                    int* __restrict__ bsum) {
    __shared__ int sd[256];
    int t = threadIdx.x, b = blockIdx.x;
    int base = b * 1024 + t * 4;
    int s = 0;
#pragma unroll
    for (int u = 0; u < 4; ++u) { int i = base + u; if (i < NN) s += hist[i]; }
    sd[t] = s;
    __syncthreads();
    for (int off = 128; off > 0; off >>= 1) {
        if (t < off) sd[t] += sd[t + off];
        __syncthreads();
    }
    if (t == 0) bsum[b] = sd[0];
}

// ---------------- scan stage 2 (fallback) ----------------
__global__ void scan2_kernel(const int* __restrict__ bsum, int* __restrict__ boff,
                             int* __restrict__ rowst) {
    if (threadIdx.x == 0 && blockIdx.x == 0) {
        int acc = 0;
        for (int i = 0; i < SCAN_NB; ++i) { boff[i] = acc; acc += bsum[i]; }
        rowst[NN] = acc;   // == EE
    }
}

// ---------------- scan stage 3 (fallback) ----------------
__global__ __launch_bounds__(256) void scan3_kernel(const int* __restrict__ hist,
                                                    const int* __restrict__ boff,
                                                    int* __restrict__ rowst) {
    __shared__ int sd[256];
    int t = threadIdx.x, b = blockIdx.x;
    int base = b * 1024 + t * 4;
    int v[4]; int s = 0;
#pragma unroll
    for (int u = 0; u < 4; ++u) {
        int i = base + u;
        v[u] = (i < NN) ? hist[i] : 0;
        s += v[u];
    }
    sd[t] = s;
    __syncthreads();
    for (int off = 1; off < 256; off <<= 1) {
        int a = (t >= off) ? sd[t - off] : 0;
        __syncthreads();
        sd[t] += a;
        __syncthreads();
    }
    int texcl = sd[t] - s;
    int o = boff[b] + texcl;
#pragma unroll
    for (int u = 0; u < 4; ++u) {
        int i = base + u;
        if (i < NN) rowst[i] = o;
        o += v[u];
    }
}

// ---------------- CSR fill: 3 independent edge streams/thread, 2048 blocks ----------------
// Concurrency = occupancy x ILP is the lever: fill is atomic-round-trip-latency-bound.
// padded: slot = (dst<<6)+pos ; compact: slot = rowst[dst]+pos
__global__ __launch_bounds__(256) void fill_kernel(const int* __restrict__ ei,
                                                   const float* __restrict__ ea,
                                                   const int* __restrict__ rowst,
                                                   int* __restrict__ fill,
                                                   float4* __restrict__ pack,
                                                   int padded) {
    const int T = FILL_NB * 256;                 // 524288 threads total
    int t0 = blockIdx.x * 256 + threadIdx.x;
    int e[3] = { t0, t0 + T, t0 + 2 * T };       // e[0],e[1] always < EE; e[2] guarded
    int d[3]; float4 p[3]; bool v[3];
#pragma unroll
    for (int u = 0; u < 3; ++u) {
        v[u] = (e[u] < EE);
        if (v[u]) {
            int s = ei[e[u]];
            d[u] = ei[EE + e[u]];
            p[u].x = ea[e[u] * 3 + 0];
            p[u].y = ea[e[u] * 3 + 1];
            p[u].z = ea[e[u] * 3 + 2];
            p[u].w = __int_as_float(s);
        }
    }
    int pos[3];
#pragma unroll
    for (int u = 0; u < 3; ++u)
        if (v[u]) pos[u] = atomicAdd(&fill[d[u]], 1);
#pragma unroll
    for (int u = 0; u < 3; ++u) {
        if (v[u]) {
            if (padded) {
                if (pos[u] < PSTR) pack[((size_t)d[u] << 6) + pos[u]] = p[u];
            } else {
                pack[rowst[d[u]] + pos[u]] = p[u];
            }
        }
    }
}

// ---------------- weighted degree: 16-lane group per node, parallel row-sum ----------------
__global__ __launch_bounds__(256) void degdinv_kernel(const float4* __restrict__ pack,
                                                      const int* __restrict__ rowst,
                                                      const int* __restrict__ cnt,
                                                      float* __restrict__ dinv,
                                                      int padded) {
    int n   = (blockIdx.x * 256 + threadIdx.x) >> 4;   // 16-lane group per node
    int sub = threadIdx.x & 15;
    if (n >= NN) return;
    int s0 = padded ? (n << 6) : rowst[n];
    int s1 = padded ? (s0 + cnt[n]) : rowst[n + 1];
    float d0 = 0.f, d1 = 0.f, d2 = 0.f;
    for (int s = s0 + sub; s < s1; s += 16) {
        float4 p = pack[s];
        d0 += p.x; d1 += p.y; d2 += p.z;
    }
#pragma unroll
    for (int off = 8; off > 0; off >>= 1) {
        d0 += __shfl_down(d0, off, 16);
        d1 += __shfl_down(d1, off, 16);
        d2 += __shfl_down(d2, off, 16);
    }
    if (sub == 0) {
        d0 += 1.0f; d1 += 1.0f; d2 += 1.0f;   // self-loop weight 1
        dinv[n]          = 1.0f / sqrtf(d0);  // deg >= 1 always
        dinv[NN + n]     = 1.0f / sqrtf(d1);
        dinv[2 * NN + n] = 1.0f / sqrtf(d2);
    }
}

// ---------------- fold SOURCE-side dinv into pack (node-parallel over rows) ----------------
__global__ __launch_bounds__(256) void normpack_kernel(const float* __restrict__ dinv,
                                                       const int* __restrict__ rowst,
                                                       const int* __restrict__ cnt,
                                                       float4* __restrict__ pack,
                                                       int padded) {
    int n   = (blockIdx.x * 256 + threadIdx.x) >> 4;
    int sub = threadIdx.x & 15;
    if (n >= NN) return;
    int s0 = padded ? (n << 6) : rowst[n];
    int s1 = padded ? (s0 + cnt[n]) : rowst[n + 1];
    for (int s = s0 + sub; s < s1; s += 16) {
        float4 p = pack[s];
        int src = __float_as_int(p.w);
        p.x *= dinv[src];
        p.y *= dinv[NN + src];
        p.z *= dinv[2 * NN + src];
        pack[s] = p;
    }
}

// ---------------- aggregation: one wave per node, branch-free masked 8-batches ----------------
__global__ __launch_bounds__(256) void agg_kernel(const float* __restrict__ h,
                                                  const float4* __restrict__ pack,
                                                  const int* __restrict__ rowst,
                                                  const int* __restrict__ cnt,
                                                  const float* __restrict__ dinv,
                                                  float* __restrict__ agg,
                                                  int padded) {
    int n = (blockIdx.x * 256 + threadIdx.x) >> 6;
    int lane = threadIdx.x & 63;
    if (n >= NN) return;
    float d0 = dinv[n], d1 = dinv[NN + n], d2 = dinv[2 * NN + n];
    float hs = h[(size_t)n * 64 + lane];
    float a0 = hs * d0;     // self-loop: src-side factor = dinv_k[n]
    float a1 = hs * d1;
    float a2 = hs * d2;
    int s0 = padded ? (n << 6) : rowst[n];
    int s1 = padded ? (s0 + cnt[n]) : rowst[n + 1];
    // branch-free: every iteration issues a full 8-deep gather batch;
    // out-of-row slots are clamped to s0 (valid edge) and masked with weight 0.
    for (int s = s0; s < s1; s += 8) {
        float4 p[8];
#pragma unroll
        for (int u = 0; u < 8; ++u) {
            int idx = s + u;
            p[u] = pack[(idx < s1) ? idx : s0];
        }
        float hv[8];
#pragma unroll
        for (int u = 0; u < 8; ++u)
            hv[u] = h[(size_t)__float_as_int(p[u].w) * 64 + lane];
#pragma unroll
        for (int u = 0; u < 8; ++u) {
            float m = (s + u < s1) ? 1.f : 0.f;
            a0 = fmaf(hv[u], p[u].x * m, a0);
            a1 = fmaf(hv[u], p[u].y * m, a1);
            a2 = fmaf(hv[u], p[u].z * m, a2);
        }
    }
    agg[(size_t)n * 192 + lane]       = a0 * d0;
    agg[(size_t)n * 192 + 64 + lane]  = a1 * d1;
    agg[(size_t)n * 192 + 128 + lane] = a2 * d2;
}

// ---------------- fused GEMM: h_new = relu?(agg[N,192]@Wcat[192,64] + bsum) + h ----------------
__global__ __launch_bounds__(256) void gemm_kernel(const float* __restrict__ agg,
                                                   const float* __restrict__ convW,
                                                   const float* __restrict__ convb,
                                                   float* __restrict__ h,
                                                   int layer, int dorelu) {
    __shared__ float an[64][68];    // agg chunk [node][k]   (+pad)
    __shared__ float ws[64][64];    // W chunk   [k][col]
    int t = threadIdx.x;
    int n0 = blockIdx.x * 64;
    const float* W = convW + (size_t)layer * 192 * 64;
    const float* B = convb + (size_t)layer * 192;
    int nb = t >> 4, cb = t & 15;
    float acc[4][4] = {{0.f}};

    for (int kc = 0; kc < 3; ++kc) {
        __syncthreads();
#pragma unroll
        for (int rep = 0; rep < 16; ++rep) {
            int flat = rep * 256 + t;        // 0..4095
            int r = flat >> 6, i = flat & 63;
            int n = n0 + r;
            an[r][i] = (n < NN) ? agg[(size_t)n * 192 + kc * 64 + i] : 0.f;
            ((float*)ws)[flat] = W[kc * 4096 + flat];
        }
        __syncthreads();
#pragma unroll 4
        for (int i = 0; i < 64; ++i) {
            float4 wv = *(const float4*)&ws[i][cb * 4];
#pragma unroll
            for (int r = 0; r < 4; ++r) {
                float a = an[nb * 4 + r][i];
                acc[r][0] = fmaf(a, wv.x, acc[r][0]);
                acc[r][1] = fmaf(a, wv.y, acc[r][1]);
                acc[r][2] = fmaf(a, wv.z, acc[r][2]);
                acc[r][3] = fmaf(a, wv.w, acc[r][3]);
            }
        }
    }

    int col0 = cb * 4;
    float bs[4];
#pragma unroll
    for (int c = 0; c < 4; ++c) {
        int col = col0 + c;
        bs[c] = B[col] + B[64 + col] + B[128 + col];
    }
#pragma unroll
    for (int r = 0; r < 4; ++r) {
        int n = n0 + nb * 4 + r;
        if (n < NN) {
            float4 hv = *(const float4*)&h[(size_t)n * 64 + col0];
            float v0 = acc[r][0] + bs[0];
            float v1 = acc[r][1] + bs[1];
            float v2 = acc[r][2] + bs[2];
            float v3 = acc[r][3] + bs[3];
            if (dorelu) {
                v0 = fmaxf(v0, 0.f); v1 = fmaxf(v1, 0.f);
                v2 = fmaxf(v2, 0.f); v3 = fmaxf(v3, 0.f);
            }
            float4 o;
            o.x = v0 + hv.x; o.y = v1 + hv.y; o.z = v2 + hv.z; o.w = v3 + hv.w;
            *(float4*)&h[(size_t)n * 64 + col0] = o;
        }
    }
}

// ---------------- graph start offsets via binary search (batch is sorted) ----------------
__global__ __launch_bounds__(256) void gstart_kernel(const int* __restrict__ batch,
                                                     int* __restrict__ gstart) {
    int g = blockIdx.x * 256 + threadIdx.x;
    if (g > GG) return;
    int lo = 0, hi = NN;
    while (lo < hi) {
        int mid = (lo + hi) >> 1;
        if (batch[mid] < g) lo = mid + 1; else hi = mid;
    }
    gstart[g] = lo;
}

// ---------------- mean pool: one block (4 waves) per graph ----------------
__global__ __launch_bounds__(256) void pool_kernel(const float* __restrict__ h,
                                                   const int* __restrict__ gstart,
                                                   float* __restrict__ hg) {
    __shared__ float red[3][64];
    int g = blockIdx.x;
    int w = threadIdx.x >> 6, lane = threadIdx.x & 63;
    int s = gstart[g], e = gstart[g + 1];
    float sum = 0.f;
    for (int n = s + w; n < e; n += 4) sum += h[(size_t)n * 64 + lane];
    if (w) red[w - 1][lane] = sum;
    __syncthreads();
    if (w == 0) {
        sum += red[0][lane] + red[1][lane] + red[2][lane];
        int c = e - s;
        hg[(size_t)g * 64 + lane] = sum / (float)(c > 0 ? c : 1);
    }
}

// ---------------- fc: 3 stacked linears, one wave per graph ----------------
__global__ __launch_bounds__(256) void fc_kernel(const float* __restrict__ hg,
                                                 const float* __restrict__ W1, const float* __restrict__ b1,
                                                 const float* __restrict__ W2, const float* __restrict__ b2,
                                                 const float* __restrict__ W3, const float* __restrict__ b3,
                                                 float* __restrict__ out) {
    int g = (blockIdx.x * 256 + threadIdx.x) >> 6;
    int lane = threadIdx.x & 63;
    if (g >= GG) return;
    float x = hg[(size_t)g * 64 + lane];
    float t1 = b1[lane];
    for (int i = 0; i < 64; ++i) t1 = fmaf(__shfl(x, i, 64), W1[i * 64 + lane], t1);
    float t2 = b2[lane];
    for (int i = 0; i < 64; ++i) t2 = fmaf(__shfl(t1, i, 64), W2[i * 64 + lane], t2);
    float p = t2 * W3[lane];
    for (int off = 32; off > 0; off >>= 1) p += __shfl_down(p, off, 64);
    if (lane == 0) out[g] = p + b3[0];
}

extern "C" void kernel_launch(void* const* d_in, const int* in_sizes, int n_in,
                              void* d_out, int out_size, void* d_ws, size_t ws_size,
                              hipStream_t stream) {
    const int*   x_atom = (const int*)d_in[0];
    const int*   ei     = (const int*)d_in[1];
    const float* ea     = (const float*)d_in[2];
    const int*   batch  = (const int*)d_in[3];
    const float* emb    = (const float*)d_in[4];
    const float* convW  = (const float*)d_in[5];
    const float* convb  = (const float*)d_in[6];
    const float* W1 = (const float*)d_in[7];  const float* b1 = (const float*)d_in[8];
    const float* W2 = (const float*)d_in[9];  const float* b2 = (const float*)d_in[10];
    const float* W3 = (const float*)d_in[11]; const float* b3 = (const float*)d_in[12];
    float* out = (float*)d_out;

    char* p = (char*)d_ws;
    size_t used = 0;
    auto alloc = [&](size_t bytes) -> void* {
        void* r = (void*)p;
        size_t rb = (bytes + 255) & ~(size_t)255;
        p += rb; used += rb;
        return r;
    };
    float*  h     = (float*)alloc((size_t)NN * 64 * 4);       // 25.6 MB
    float*  agg   = (float*)alloc((size_t)NN * 192 * 4);      // 76.8 MB
    float*  dinv  = (float*)alloc((size_t)3 * NN * 4);        // 1.2 MB
    int*    hist  = (int*)alloc((size_t)NN * 4);
    int*    rowst = (int*)alloc((size_t)(NN + 1) * 4);
    int*    fill  = (int*)alloc((size_t)NN * 4);
    int*    bsum  = (int*)alloc(128 * 4);
    int*    boff  = (int*)alloc(128 * 4);
    int*    gstart= (int*)alloc((size_t)(GG + 1) * 4);
    float*  hg    = (float*)alloc((size_t)GG * 64 * 4);
    // pack last: padded (102.4 MB) if workspace allows, else compact (19.2 MB, +8 slot margin)
    size_t padded_bytes  = (size_t)NN * PSTR * 16;
    size_t compact_bytes = (size_t)(EE + 8) * 16;
    int padded = (ws_size >= used + padded_bytes) ? 1 : 0;
    float4* pack = (float4*)alloc(padded ? padded_bytes : compact_bytes);

    // ---- encoder + CSR build ----
    enc_kernel<<<(NN * 64) / 256, 256, 0, stream>>>(x_atom, emb, h);
    init_kernel<<<(NN + 255) / 256, 256, 0, stream>>>(hist, fill);
    if (!padded) {
        hist_kernel<<<(EE + 255) / 256, 256, 0, stream>>>(ei, hist);
        scan1_kernel<<<SCAN_NB, 256, 0, stream>>>(hist, bsum);
        scan2_kernel<<<1, 64, 0, stream>>>(bsum, boff, rowst);
        scan3_kernel<<<SCAN_NB, 256, 0, stream>>>(hist, boff, rowst);
    }
    fill_kernel<<<FILL_NB, 256, 0, stream>>>(ei, ea, rowst, fill, pack, padded);
    degdinv_kernel<<<(NN * 16 + 255) / 256, 256, 0, stream>>>(pack, rowst, fill, dinv, padded);
    normpack_kernel<<<(NN * 16 + 255) / 256, 256, 0, stream>>>(dinv, rowst, fill, pack, padded);
    gstart_kernel<<<(GG + 1 + 255) / 256, 256, 0, stream>>>(batch, gstart);

    // ---- 3 GCN layers: aggregate-then-GEMM (linearity refactor) ----
    for (int layer = 0; layer < LL; ++layer) {
        agg_kernel<<<NN / 4, 256, 0, stream>>>(h, pack, rowst, fill, dinv, agg, padded);
        gemm_kernel<<<(NN + 63) / 64, 256, 0, stream>>>(agg, convW, convb, h, layer,
                                                        (layer < LL - 1) ? 1 : 0);
    }

    // ---- pool + fc ----
    pool_kernel<<<GG, 256, 0, stream>>>(h, gstart, hg);
    fc_kernel<<<GG / 4, 256, 0, stream>>>(hg, W1, b1, W2, b2, W3, b3, out);
}